// Round 1
// baseline (170.841 us; speedup 1.0000x reference)
//
#include <hip/hip_runtime.h>

typedef unsigned short u16;
typedef unsigned int   u32;
typedef __attribute__((ext_vector_type(8))) short bf16x8;
typedef __attribute__((ext_vector_type(4))) float f32x4;

#define NC   256
#define NHW  4096
#define NM   64
#define NT   64
#define BETA 0.5f

// ---- LDS layout (bytes), all offsets 16B aligned ----
#define OFF_XZT  0         // u16[64][264]  : x^T (token-major) then z_norm / z
#define OFF_MEM  33792     // u16[64][264]  : mem_norm [m][c]
#define OFF_MEMT 67584     // u16[256][72]  : mem_norm^T [c][m]   (also f32 staging buf)
#define OFF_AS   104448    // u16[64][72]   : attn bf16 [t][m]
#define OFF_SS   113664    // f32[64][68]   : scores [t][m]
#define OFF_RINV 131072    // f32[64]
#define OFF_RED  131328    // f32[64][4]
#define SMEM_SZ  132352

__device__ __forceinline__ u16 f2bf(float f) {
  u32 u = __float_as_uint(f);
  return (u16)((u + 0x7FFFu + ((u >> 16) & 1u)) >> 16);
}
__device__ __forceinline__ u32 pack2(float a, float b) {
  return (u32)f2bf(a) | ((u32)f2bf(b) << 16);
}

// ---- prep: Wq/Wout -> bf16; mem_bank -> normalized bf16 (row-major + transposed) ----
__global__ void hop_prep(const float* __restrict__ wq_f, const float* __restrict__ wo_f,
                         const float* __restrict__ memb,
                         u16* __restrict__ wq_b, u16* __restrict__ wo_b,
                         u16* __restrict__ mem_b, u16* __restrict__ memT_b) {
  int blk = blockIdx.x, tid = threadIdx.x;
  if (blk < 32) {
    int base = blk * 2048;
    #pragma unroll
    for (int i = 0; i < 8; ++i) wq_b[base + tid + 256*i] = f2bf(wq_f[base + tid + 256*i]);
  } else if (blk < 64) {
    int base = (blk - 32) * 2048;
    #pragma unroll
    for (int i = 0; i < 8; ++i) wo_b[base + tid + 256*i] = f2bf(wo_f[base + tid + 256*i]);
  } else {
    int m = tid >> 2, part = tid & 3;
    float s = 0.f;
    for (int j = 0; j < 64; ++j) {
      float v = memb[m*NC + part*64 + j];
      s += v*v;
    }
    s += __shfl_xor(s, 1);
    s += __shfl_xor(s, 2);
    float inv = 1.0f / fmaxf(sqrtf(s), 1e-12f);
    for (int j = 0; j < 64; ++j) {
      int c = part*64 + j;
      u16 h = f2bf(memb[m*NC + c] * inv);
      mem_b[m*NC + c]  = h;
      memT_b[c*NM + m] = h;
    }
  }
}

// ---- fused main kernel: one block = 64 tokens of one image ----
__global__ __launch_bounds__(256, 1) void hop_main(
    const float* __restrict__ x, const float* __restrict__ bq,
    const float* __restrict__ bout, const u16* __restrict__ wq,
    const u16* __restrict__ wout, const u16* __restrict__ gmem,
    const u16* __restrict__ gmemT, float* __restrict__ out) {
  __shared__ __align__(16) char smem[SMEM_SZ];
  u16  (*XZT)[264] = (u16 (*)[264])(smem + OFF_XZT);
  u16  (*Mem)[264] = (u16 (*)[264])(smem + OFF_MEM);
  u16  (*MemT)[72] = (u16 (*)[72])(smem + OFF_MEMT);
  u16  (*As)[72]   = (u16 (*)[72])(smem + OFF_AS);
  float(*Ss)[68]   = (float(*)[68])(smem + OFF_SS);
  float *Rinv      = (float*)(smem + OFF_RINV);
  float(*Red)[4]   = (float(*)[4])(smem + OFF_RED);

  const int tid = threadIdx.x;
  const int w  = tid >> 6;   // wave 0..3
  const int l  = tid & 63;
  const int lg = l >> 4;     // 0..3
  const int ll = l & 15;

  const int bimg = blockIdx.x >> 6;
  const int t0   = (blockIdx.x & 63) * NT;
  const float* xb = x   + (size_t)bimg * NC * NHW + t0;
  float*       ob = out + (size_t)bimg * NC * NHW + t0;

  // ---- stage x -> XZT bf16 token-major, via f32 transpose buffer (in MemT region) ----
  {
    float (*Buf)[72] = (float (*)[72])(smem + OFF_MEMT); // 64x72 f32 = 18KB
    for (int ci = 0; ci < 4; ++ci) {
      const float* xc = xb + (size_t)(64*ci) * NHW;
      #pragma unroll
      for (int p = 0; p < 4; ++p) {
        int row = p*16 + (tid >> 4);
        int f4  = (tid & 15) * 4;
        float4 v = *(const float4*)(xc + (size_t)row * NHW + f4);
        *(float4*)&Buf[row][f4] = v;
      }
      __syncthreads();
      {
        int t = tid & 63;
        int q = tid >> 6;
        #pragma unroll
        for (int k = 0; k < 16; k += 2) {
          int cl = 16*q + k;
          *(u32*)&XZT[t][64*ci + cl] = pack2(Buf[cl][t], Buf[cl+1][t]);
        }
      }
      __syncthreads();
    }
  }
  // ---- load normalized memory bank (both orientations) into LDS ----
  for (int i = tid; i < 64*128; i += 256) {
    int m = i >> 7, j = i & 127;
    ((u32*)&Mem[m][0])[j] = ((const u32*)gmem)[i];
  }
  for (int i = tid; i < 256*32; i += 256) {
    int c = i >> 5, j = i & 31;
    ((u32*)&MemT[c][0])[j] = ((const u32*)gmemT)[i];
  }
  float bq_r[4], bo_r[4];
  #pragma unroll
  for (int ni = 0; ni < 4; ++ni) {
    bq_r[ni] = bq[64*w + 16*ni + ll];
    bo_r[ni] = bout[64*w + 16*ni + ll];
  }
  __syncthreads();

  // ---- GEMM1: z[t][o] = sum_c x^T[t][c] * Wq[o][c]  (wave w owns o in [64w,64w+64)) ----
  f32x4 z[4][4];
  #pragma unroll
  for (int mi = 0; mi < 4; ++mi)
    #pragma unroll
    for (int ni = 0; ni < 4; ++ni) z[mi][ni] = (f32x4){0.f,0.f,0.f,0.f};
  {
    const u16* wrow0 = wq + (size_t)(64*w + ll) * NC;
    #pragma unroll
    for (int kk = 0; kk < 8; ++kk) {
      int c0 = 32*kk + 8*lg;
      bf16x8 a[4], b[4];
      #pragma unroll
      for (int mi = 0; mi < 4; ++mi) a[mi] = *(const bf16x8*)&XZT[16*mi + ll][c0];
      #pragma unroll
      for (int ni = 0; ni < 4; ++ni) b[ni] = *(const bf16x8*)(wrow0 + (size_t)(16*ni)*NC + c0);
      #pragma unroll
      for (int mi = 0; mi < 4; ++mi)
        #pragma unroll
        for (int ni = 0; ni < 4; ++ni)
          z[mi][ni] = __builtin_amdgcn_mfma_f32_16x16x32_bf16(a[mi], b[ni], z[mi][ni], 0, 0, 0);
    }
  }
  #pragma unroll
  for (int mi = 0; mi < 4; ++mi)
    #pragma unroll
    for (int ni = 0; ni < 4; ++ni)
      #pragma unroll
      for (int r = 0; r < 4; ++r) z[mi][ni][r] += bq_r[ni];

  // ---- rinv computation (per-token 1/max(||z||,eps)) ----
  auto compute_rinv = [&]() {
    #pragma unroll
    for (int mi = 0; mi < 4; ++mi) {
      #pragma unroll
      for (int r = 0; r < 4; ++r) {
        float v = 0.f;
        #pragma unroll
        for (int ni = 0; ni < 4; ++ni) { float e = z[mi][ni][r]; v += e*e; }
        v += __shfl_xor(v, 1); v += __shfl_xor(v, 2);
        v += __shfl_xor(v, 4); v += __shfl_xor(v, 8);
        if (ll == 0) Red[16*mi + 4*lg + r][w] = v;
      }
    }
    __syncthreads();
    if (tid < 64) {
      float tot = Red[tid][0] + Red[tid][1] + Red[tid][2] + Red[tid][3];
      Rinv[tid] = 1.0f / fmaxf(sqrtf(tot), 1e-12f);
    }
    __syncthreads();
  };

  // z = l2norm(q)
  compute_rinv();
  #pragma unroll
  for (int mi = 0; mi < 4; ++mi)
    #pragma unroll
    for (int r = 0; r < 4; ++r) {
      float rv = Rinv[16*mi + 4*lg + r];
      #pragma unroll
      for (int ni = 0; ni < 4; ++ni) z[mi][ni][r] *= rv;
    }

  // ---- Hopfield iterations ----
  for (int it = 0; it < 3; ++it) {
    compute_rinv();
    // write z_norm bf16 to XZT
    #pragma unroll
    for (int mi = 0; mi < 4; ++mi)
      #pragma unroll
      for (int r = 0; r < 4; ++r) {
        int t = 16*mi + 4*lg + r;
        float rv = Rinv[t];
        #pragma unroll
        for (int ni = 0; ni < 4; ++ni)
          XZT[t][64*w + 16*ni + ll] = f2bf(z[mi][ni][r] * rv);
      }
    __syncthreads();

    // S[t][m] = z_norm . mem_norm   (wave w owns m in [16w,16w+16))
    f32x4 s[4];
    #pragma unroll
    for (int mi = 0; mi < 4; ++mi) s[mi] = (f32x4){0.f,0.f,0.f,0.f};
    #pragma unroll
    for (int kk = 0; kk < 8; ++kk) {
      int c0 = 32*kk + 8*lg;
      bf16x8 bm = *(const bf16x8*)&Mem[16*w + ll][c0];
      #pragma unroll
      for (int mi = 0; mi < 4; ++mi) {
        bf16x8 a = *(const bf16x8*)&XZT[16*mi + ll][c0];
        s[mi] = __builtin_amdgcn_mfma_f32_16x16x32_bf16(a, bm, s[mi], 0, 0, 0);
      }
    }
    #pragma unroll
    for (int mi = 0; mi < 4; ++mi)
      #pragma unroll
      for (int r = 0; r < 4; ++r)
        Ss[16*mi + 4*lg + r][16*w + ll] = s[mi][r];
    __syncthreads();

    // softmax over m per token; write attn bf16 to As
    {
      int t = tid >> 2, part = tid & 3;
      float e[16];
      float mx = -1e30f;
      #pragma unroll
      for (int i = 0; i < 16; ++i) { e[i] = Ss[t][16*part + i]; mx = fmaxf(mx, e[i]); }
      mx = fmaxf(mx, __shfl_xor(mx, 1));
      mx = fmaxf(mx, __shfl_xor(mx, 2));
      float sum = 0.f;
      #pragma unroll
      for (int i = 0; i < 16; ++i) { e[i] = __expf(e[i] - mx); sum += e[i]; }
      sum += __shfl_xor(sum, 1);
      sum += __shfl_xor(sum, 2);
      float inv = 1.0f / sum;
      #pragma unroll
      for (int i = 0; i < 16; i += 2)
        *(u32*)&As[t][16*part + i] = pack2(e[i]*inv, e[i+1]*inv);
    }
    __syncthreads();

    // G[t][c] = attn . mem_norm   (wave w owns c in [64w,64w+64))
    f32x4 g[4][4];
    #pragma unroll
    for (int mi = 0; mi < 4; ++mi)
      #pragma unroll
      for (int ni = 0; ni < 4; ++ni) g[mi][ni] = (f32x4){0.f,0.f,0.f,0.f};
    #pragma unroll
    for (int kk = 0; kk < 2; ++kk) {
      int m0 = 32*kk + 8*lg;
      bf16x8 a[4], b[4];
      #pragma unroll
      for (int mi = 0; mi < 4; ++mi) a[mi] = *(const bf16x8*)&As[16*mi + ll][m0];
      #pragma unroll
      for (int ni = 0; ni < 4; ++ni) b[ni] = *(const bf16x8*)&MemT[64*w + 16*ni + ll][m0];
      #pragma unroll
      for (int mi = 0; mi < 4; ++mi)
        #pragma unroll
        for (int ni = 0; ni < 4; ++ni)
          g[mi][ni] = __builtin_amdgcn_mfma_f32_16x16x32_bf16(a[mi], b[ni], g[mi][ni], 0, 0, 0);
    }
    // z = (1-beta)*z + beta*G
    #pragma unroll
    for (int mi = 0; mi < 4; ++mi)
      #pragma unroll
      for (int ni = 0; ni < 4; ++ni)
        #pragma unroll
        for (int r = 0; r < 4; ++r)
          z[mi][ni][r] = (1.0f - BETA) * z[mi][ni][r] + BETA * g[mi][ni][r];
  }

  // ---- write raw z bf16 to XZT for the output GEMM ----
  #pragma unroll
  for (int mi = 0; mi < 4; ++mi)
    #pragma unroll
    for (int r = 0; r < 4; ++r) {
      int t = 16*mi + 4*lg + r;
      #pragma unroll
      for (int ni = 0; ni < 4; ++ni)
        XZT[t][64*w + 16*ni + ll] = f2bf(z[mi][ni][r]);
    }
  __syncthreads();

  // ---- final GEMM: o[t][o] = sum_c z[t][c] * Wout[o][c] ----
  f32x4 oa[4][4];
  #pragma unroll
  for (int mi = 0; mi < 4; ++mi)
    #pragma unroll
    for (int ni = 0; ni < 4; ++ni) oa[mi][ni] = (f32x4){0.f,0.f,0.f,0.f};
  {
    const u16* wrow0 = wout + (size_t)(64*w + ll) * NC;
    #pragma unroll
    for (int kk = 0; kk < 8; ++kk) {
      int c0 = 32*kk + 8*lg;
      bf16x8 a[4], b[4];
      #pragma unroll
      for (int mi = 0; mi < 4; ++mi) a[mi] = *(const bf16x8*)&XZT[16*mi + ll][c0];
      #pragma unroll
      for (int ni = 0; ni < 4; ++ni) b[ni] = *(const bf16x8*)(wrow0 + (size_t)(16*ni)*NC + c0);
      #pragma unroll
      for (int mi = 0; mi < 4; ++mi)
        #pragma unroll
        for (int ni = 0; ni < 4; ++ni)
          oa[mi][ni] = __builtin_amdgcn_mfma_f32_16x16x32_bf16(a[mi], b[ni], oa[mi][ni], 0, 0, 0);
    }
  }
  #pragma unroll
  for (int mi = 0; mi < 4; ++mi)
    #pragma unroll
    for (int ni = 0; ni < 4; ++ni)
      #pragma unroll
      for (int r = 0; r < 4; ++r) oa[mi][ni][r] += bo_r[ni];

  // ---- transpose back via per-wave LDS buffer (Mem region, now dead) + residual + store ----
  float (*OB)[20] = (float (*)[20])(smem + OFF_MEM + (size_t)w * (64*20*4)); // 5KB per wave
  for (int ni = 0; ni < 4; ++ni) {
    __syncthreads();
    #pragma unroll
    for (int mi = 0; mi < 4; ++mi)
      #pragma unroll
      for (int r = 0; r < 4; ++r)
        OB[16*mi + 4*lg + r][ll] = oa[mi][ni][r];
    __syncthreads();
    int ol = l >> 2, tq = l & 3;
    int o = 64*w + 16*ni + ol;
    const float* xr = xb + (size_t)o * NHW;
    float*       orow = ob + (size_t)o * NHW;
    #pragma unroll
    for (int ii = 0; ii < 4; ++ii) {
      int tloc = 16*tq + 4*ii;
      float4 vx = *(const float4*)(xr + tloc);
      float4 vo;
      vo.x = OB[tloc+0][ol] + vx.x;
      vo.y = OB[tloc+1][ol] + vx.y;
      vo.z = OB[tloc+2][ol] + vx.z;
      vo.w = OB[tloc+3][ol] + vx.w;
      *(float4*)(orow + tloc) = vo;
    }
  }
}

extern "C" void kernel_launch(void* const* d_in, const int* in_sizes, int n_in,
                              void* d_out, int out_size, void* d_ws, size_t ws_size,
                              hipStream_t stream) {
  const float* x    = (const float*)d_in[0];
  const float* memb = (const float*)d_in[1];
  const float* Wq   = (const float*)d_in[2];
  const float* bq   = (const float*)d_in[3];
  const float* Wout = (const float*)d_in[4];
  const float* bout = (const float*)d_in[5];
  float* out = (float*)d_out;

  u16* wq_b   = (u16*)d_ws;
  u16* wout_b = wq_b + 65536;
  u16* mem_b  = wq_b + 131072;
  u16* memT_b = wq_b + 131072 + 16384;

  hop_prep<<<65, 256, 0, stream>>>(Wq, Wout, memb, wq_b, wout_b, mem_b, memT_b);
  hop_main<<<1024, 256, 0, stream>>>(x, bq, bout, wq_b, wout_b, mem_b, memT_b, out);
}

// Round 2
// 142.360 us; speedup vs baseline: 1.2001x; 1.2001x over previous
//
#include <hip/hip_runtime.h>

typedef unsigned short u16;
typedef unsigned int   u32;
typedef __attribute__((ext_vector_type(8))) short bf16x8;
typedef __attribute__((ext_vector_type(4))) float f32x4;

#define NC   256
#define NHW  4096
#define NM   64
#define NT   32      // tokens per block
#define XR   264     // XZT row stride (u16): 528B, 16B-aligned, frag reads conflict-free

// ---- LDS layout (bytes) ----
#define OFF_XZT   0        // u16[32][264] : x^T / z_norm / z  (token-major)  16,896 B
#define OFF_UNION 16896    // As u16[32][72] (4,608 B)  OR  OB f32[4][32][17] (8,704 B)
#define OFF_STATR 25600    // f32[32][4]   rinv partials
#define OFF_STATS 26112    // f32[32][8]   softmax {max,sum} pairs per wave
#define SMEM_SZ   27136

__device__ __forceinline__ u16 f2bf(float f) {
  u32 u = __float_as_uint(f);
  return (u16)((u + 0x7FFFu + ((u >> 16) & 1u)) >> 16);
}

// ---- prep: Wq/Wout -> bf16; mem_bank -> normalized bf16 (row-major + transposed) ----
__global__ void hop_prep(const float* __restrict__ wq_f, const float* __restrict__ wo_f,
                         const float* __restrict__ memb,
                         u16* __restrict__ wq_b, u16* __restrict__ wo_b,
                         u16* __restrict__ mem_b, u16* __restrict__ memT_b) {
  int blk = blockIdx.x, tid = threadIdx.x;
  if (blk < 32) {
    int base = blk * 2048;
    #pragma unroll
    for (int i = 0; i < 8; ++i) wq_b[base + tid + 256*i] = f2bf(wq_f[base + tid + 256*i]);
  } else if (blk < 64) {
    int base = (blk - 32) * 2048;
    #pragma unroll
    for (int i = 0; i < 8; ++i) wo_b[base + tid + 256*i] = f2bf(wo_f[base + tid + 256*i]);
  } else {
    int m = tid >> 2, part = tid & 3;
    float s = 0.f;
    for (int j = 0; j < 64; ++j) {
      float v = memb[m*NC + part*64 + j];
      s += v*v;
    }
    s += __shfl_xor(s, 1);
    s += __shfl_xor(s, 2);
    float inv = 1.0f / fmaxf(sqrtf(s), 1e-12f);
    for (int j = 0; j < 64; ++j) {
      int c = part*64 + j;
      u16 h = f2bf(memb[m*NC + c] * inv);
      mem_b[m*NC + c]  = h;
      memT_b[c*NM + m] = h;
    }
  }
}

// ---- fused main kernel: one block = 32 tokens ----
__global__ __launch_bounds__(256, 3) void hop_main(
    const float* __restrict__ x, const float* __restrict__ bq,
    const float* __restrict__ bout, const u16* __restrict__ wq,
    const u16* __restrict__ wout, const u16* __restrict__ gmem,
    const u16* __restrict__ gmemT, float* __restrict__ out) {
  __shared__ __align__(16) char smem[SMEM_SZ];
  u16  (*XZT)[XR]  = (u16 (*)[XR])(smem + OFF_XZT);
  u16  (*As)[72]   = (u16 (*)[72])(smem + OFF_UNION);
  float(*StatR)[4] = (float(*)[4])(smem + OFF_STATR);
  float(*StatS)[8] = (float(*)[8])(smem + OFF_STATS);

  const int tid = threadIdx.x;
  const int w  = tid >> 6;   // wave 0..3
  const int l  = tid & 63;
  const int lg = l >> 4;     // 0..3
  const int ll = l & 15;

  const int bimg = blockIdx.x >> 7;            // 128 blocks per image
  const int t0   = (blockIdx.x & 127) * NT;
  const float* xb = x   + (size_t)bimg * NC * NHW + t0;
  float*       ob = out + (size_t)bimg * NC * NHW + t0;

  // ---- stage x -> XZT bf16 token-major (direct, float2 loads) ----
  {
    int cg = tid >> 4;          // 0..15
    int t2 = (tid & 15) * 2;
    #pragma unroll
    for (int k = 0; k < 16; ++k) {
      int c = 16*k + cg;
      float2 v = *(const float2*)(xb + (size_t)c * NHW + t2);
      XZT[t2][c]   = f2bf(v.x);
      XZT[t2+1][c] = f2bf(v.y);
    }
  }
  float bq_r[4], bo_r[4];
  #pragma unroll
  for (int ni = 0; ni < 4; ++ni) {
    bq_r[ni] = bq[64*w + 16*ni + ll];
    bo_r[ni] = bout[64*w + 16*ni + ll];
  }
  __syncthreads();

  // ---- GEMM1: z[t][o] = sum_c x^T[t][c] * Wq[o][c]  (wave w owns o in [64w,64w+64)) ----
  f32x4 z[2][4];
  #pragma unroll
  for (int mi = 0; mi < 2; ++mi)
    #pragma unroll
    for (int ni = 0; ni < 4; ++ni) z[mi][ni] = (f32x4){0.f,0.f,0.f,0.f};
  {
    const u16* wrow0 = wq + (size_t)(64*w + ll) * NC + 8*lg;
    #pragma unroll
    for (int kk = 0; kk < 8; ++kk) {
      bf16x8 a[2], b[4];
      #pragma unroll
      for (int mi = 0; mi < 2; ++mi) a[mi] = *(const bf16x8*)&XZT[16*mi + ll][32*kk + 8*lg];
      #pragma unroll
      for (int ni = 0; ni < 4; ++ni) b[ni] = *(const bf16x8*)(wrow0 + (size_t)(16*ni)*NC + 32*kk);
      #pragma unroll
      for (int mi = 0; mi < 2; ++mi)
        #pragma unroll
        for (int ni = 0; ni < 4; ++ni)
          z[mi][ni] = __builtin_amdgcn_mfma_f32_16x16x32_bf16(a[mi], b[ni], z[mi][ni], 0, 0, 0);
    }
  }
  #pragma unroll
  for (int mi = 0; mi < 2; ++mi)
    #pragma unroll
    for (int ni = 0; ni < 4; ++ni)
      #pragma unroll
      for (int r = 0; r < 4; ++r) z[mi][ni][r] += bq_r[ni];

  // ---- preload memory-bank fragments into registers (loop-invariant) ----
  bf16x8 memf[8];        // S-GEMM B-frags: Mem[16w+ll][32kk+8lg..+8]
  {
    const u16* mrow = gmem + (size_t)(16*w + ll) * NC + 8*lg;
    #pragma unroll
    for (int kk = 0; kk < 8; ++kk) memf[kk] = *(const bf16x8*)(mrow + 32*kk);
  }
  bf16x8 mtf[2][4];      // G-GEMM B-frags: MemT[64w+16ni+ll][32kk+8lg..+8]
  #pragma unroll
  for (int ni = 0; ni < 4; ++ni) {
    const u16* mtrow = gmemT + (size_t)(64*w + 16*ni + ll) * NM + 8*lg;
    #pragma unroll
    for (int kk = 0; kk < 2; ++kk) mtf[kk][ni] = *(const bf16x8*)(mtrow + 32*kk);
  }

  // ---- q-norm: z = l2norm(q)  (exchange via StatS) ----
  {
    #pragma unroll
    for (int mi = 0; mi < 2; ++mi)
      #pragma unroll
      for (int r = 0; r < 4; ++r) {
        float v = 0.f;
        #pragma unroll
        for (int ni = 0; ni < 4; ++ni) { float e = z[mi][ni][r]; v += e*e; }
        v += __shfl_xor(v, 1); v += __shfl_xor(v, 2);
        v += __shfl_xor(v, 4); v += __shfl_xor(v, 8);
        if (ll == 0) StatS[16*mi + 4*lg + r][w] = v;
      }
    __syncthreads();
    #pragma unroll
    for (int mi = 0; mi < 2; ++mi)
      #pragma unroll
      for (int r = 0; r < 4; ++r) {
        int t = 16*mi + 4*lg + r;
        float4 p = *(const float4*)&StatS[t][0];
        float rv = 1.0f / fmaxf(sqrtf(p.x + p.y + p.z + p.w), 1e-12f);
        #pragma unroll
        for (int ni = 0; ni < 4; ++ni) z[mi][ni][r] *= rv;
      }
  }

  // ---- Hopfield iterations ----
  for (int it = 0; it < 3; ++it) {
    // 1. rinv partials
    #pragma unroll
    for (int mi = 0; mi < 2; ++mi)
      #pragma unroll
      for (int r = 0; r < 4; ++r) {
        float v = 0.f;
        #pragma unroll
        for (int ni = 0; ni < 4; ++ni) { float e = z[mi][ni][r]; v += e*e; }
        v += __shfl_xor(v, 1); v += __shfl_xor(v, 2);
        v += __shfl_xor(v, 4); v += __shfl_xor(v, 8);
        if (ll == 0) StatR[16*mi + 4*lg + r][w] = v;
      }
    __syncthreads();   // A
    // 2. z_norm -> XZT
    #pragma unroll
    for (int mi = 0; mi < 2; ++mi)
      #pragma unroll
      for (int r = 0; r < 4; ++r) {
        int t = 16*mi + 4*lg + r;
        float4 p = *(const float4*)&StatR[t][0];
        float rv = 1.0f / fmaxf(sqrtf(p.x + p.y + p.z + p.w), 1e-12f);
        #pragma unroll
        for (int ni = 0; ni < 4; ++ni)
          XZT[t][64*w + 16*ni + ll] = f2bf(z[mi][ni][r] * rv);
      }
    __syncthreads();   // B
    // 3. S GEMM: S[t][m], wave w owns m in [16w,16w+16)
    f32x4 s[2];
    #pragma unroll
    for (int mi = 0; mi < 2; ++mi) s[mi] = (f32x4){0.f,0.f,0.f,0.f};
    #pragma unroll
    for (int kk = 0; kk < 8; ++kk) {
      #pragma unroll
      for (int mi = 0; mi < 2; ++mi) {
        bf16x8 a = *(const bf16x8*)&XZT[16*mi + ll][32*kk + 8*lg];
        s[mi] = __builtin_amdgcn_mfma_f32_16x16x32_bf16(a, memf[kk], s[mi], 0, 0, 0);
      }
    }
    // 4. softmax partials (max & sum over this wave's 16 m's per token)
    float pm[2][4], ps[2][4];
    #pragma unroll
    for (int mi = 0; mi < 2; ++mi)
      #pragma unroll
      for (int r = 0; r < 4; ++r) {
        float mx = s[mi][r];
        mx = fmaxf(mx, __shfl_xor(mx, 1)); mx = fmaxf(mx, __shfl_xor(mx, 2));
        mx = fmaxf(mx, __shfl_xor(mx, 4)); mx = fmaxf(mx, __shfl_xor(mx, 8));
        float e = __expf(s[mi][r] - mx);
        float sm = e;
        sm += __shfl_xor(sm, 1); sm += __shfl_xor(sm, 2);
        sm += __shfl_xor(sm, 4); sm += __shfl_xor(sm, 8);
        pm[mi][r] = mx; ps[mi][r] = sm;
        if (ll == 0) {
          int t = 16*mi + 4*lg + r;
          StatS[t][2*w]   = mx;
          StatS[t][2*w+1] = sm;
        }
      }
    __syncthreads();   // C
    // 5. finish softmax, write attn*0.5 (beta fold) to As
    #pragma unroll
    for (int mi = 0; mi < 2; ++mi)
      #pragma unroll
      for (int r = 0; r < 4; ++r) {
        int t = 16*mi + 4*lg + r;
        float4 p0 = *(const float4*)&StatS[t][0];
        float4 p1 = *(const float4*)&StatS[t][4];
        float M = fmaxf(fmaxf(p0.x, p0.z), fmaxf(p1.x, p1.z));
        float Zs = p0.y * __expf(p0.x - M) + p0.w * __expf(p0.z - M)
                 + p1.y * __expf(p1.x - M) + p1.w * __expf(p1.z - M);
        float attn = __expf(s[mi][r] - M) * (0.5f / Zs);
        As[t][16*w + ll] = f2bf(attn);
      }
    __syncthreads();   // D
    // 6. G GEMM accumulated into z (z = 0.5*z + (0.5*attn)@mem)
    #pragma unroll
    for (int mi = 0; mi < 2; ++mi)
      #pragma unroll
      for (int ni = 0; ni < 4; ++ni)
        #pragma unroll
        for (int r = 0; r < 4; ++r) z[mi][ni][r] *= 0.5f;
    bf16x8 pa[2][2];
    #pragma unroll
    for (int mi = 0; mi < 2; ++mi)
      #pragma unroll
      for (int kk = 0; kk < 2; ++kk)
        pa[mi][kk] = *(const bf16x8*)&As[16*mi + ll][32*kk + 8*lg];
    #pragma unroll
    for (int kk = 0; kk < 2; ++kk)
      #pragma unroll
      for (int mi = 0; mi < 2; ++mi)
        #pragma unroll
        for (int ni = 0; ni < 4; ++ni)
          z[mi][ni] = __builtin_amdgcn_mfma_f32_16x16x32_bf16(pa[mi][kk], mtf[kk][ni], z[mi][ni], 0, 0, 0);
  }

  // ---- write raw z to XZT for the output GEMM ----
  #pragma unroll
  for (int mi = 0; mi < 2; ++mi)
    #pragma unroll
    for (int r = 0; r < 4; ++r) {
      int t = 16*mi + 4*lg + r;
      #pragma unroll
      for (int ni = 0; ni < 4; ++ni)
        XZT[t][64*w + 16*ni + ll] = f2bf(z[mi][ni][r]);
    }
  __syncthreads();   // E

  // ---- final GEMM: o[t][o] = sum_c z[t][c] * Wout[o][c] ----
  f32x4 oa[2][4];
  #pragma unroll
  for (int mi = 0; mi < 2; ++mi)
    #pragma unroll
    for (int ni = 0; ni < 4; ++ni) oa[mi][ni] = (f32x4){0.f,0.f,0.f,0.f};
  {
    const u16* wrow0 = wout + (size_t)(64*w + ll) * NC + 8*lg;
    #pragma unroll
    for (int kk = 0; kk < 8; ++kk) {
      bf16x8 a[2], b[4];
      #pragma unroll
      for (int mi = 0; mi < 2; ++mi) a[mi] = *(const bf16x8*)&XZT[16*mi + ll][32*kk + 8*lg];
      #pragma unroll
      for (int ni = 0; ni < 4; ++ni) b[ni] = *(const bf16x8*)(wrow0 + (size_t)(16*ni)*NC + 32*kk);
      #pragma unroll
      for (int mi = 0; mi < 2; ++mi)
        #pragma unroll
        for (int ni = 0; ni < 4; ++ni)
          oa[mi][ni] = __builtin_amdgcn_mfma_f32_16x16x32_bf16(a[mi], b[ni], oa[mi][ni], 0, 0, 0);
    }
  }
  #pragma unroll
  for (int mi = 0; mi < 2; ++mi)
    #pragma unroll
    for (int ni = 0; ni < 4; ++ni)
      #pragma unroll
      for (int r = 0; r < 4; ++r) oa[mi][ni][r] += bo_r[ni];

  // ---- wave-private transpose (OB) + residual + store ----
  float (*OB)[17] = (float (*)[17])(smem + OFF_UNION + (size_t)w * (NT*17*4));
  #pragma unroll
  for (int ni = 0; ni < 4; ++ni) {
    #pragma unroll
    for (int mi = 0; mi < 2; ++mi)
      #pragma unroll
      for (int r = 0; r < 4; ++r)
        OB[16*mi + 4*lg + r][ll] = oa[mi][ni][r];
    // wave-private: DS pipe processes the reads below after the writes above (program order)
    #pragma unroll
    for (int ss = 0; ss < 8; ++ss) {
      int op = 2*ss + (l >> 5);     // 0..15
      int t  = l & 31;
      int o  = 64*w + 16*ni + op;
      float v = OB[t][op];
      const float* xr = xb + (size_t)o * NHW;
      float*     orow = ob + (size_t)o * NHW;
      orow[t] = v + xr[t];
    }
  }
}

extern "C" void kernel_launch(void* const* d_in, const int* in_sizes, int n_in,
                              void* d_out, int out_size, void* d_ws, size_t ws_size,
                              hipStream_t stream) {
  const float* x    = (const float*)d_in[0];
  const float* memb = (const float*)d_in[1];
  const float* Wq   = (const float*)d_in[2];
  const float* bq   = (const float*)d_in[3];
  const float* Wout = (const float*)d_in[4];
  const float* bout = (const float*)d_in[5];
  float* out = (float*)d_out;

  u16* wq_b   = (u16*)d_ws;
  u16* wout_b = wq_b + 65536;
  u16* mem_b  = wq_b + 131072;
  u16* memT_b = wq_b + 131072 + 16384;

  hop_prep<<<65, 256, 0, stream>>>(Wq, Wout, memb, wq_b, wout_b, mem_b, memT_b);
  hop_main<<<2048, 256, 0, stream>>>(x, bq, bout, wq_b, wout_b, mem_b, memT_b, out);
}

// Round 3
// 113.814 us; speedup vs baseline: 1.5010x; 1.2508x over previous
//
#include <hip/hip_runtime.h>
#include <hip/hip_bf16.h>

typedef unsigned short u16;
typedef unsigned int   u32;
typedef __attribute__((ext_vector_type(8))) short bf16x8;
typedef __attribute__((ext_vector_type(4))) float f32x4;

#define NC  256
#define NHW 4096

// ---- LDS layout (bytes) ----
#define OFF_XZT 0        // u16[64][256] XOR-swizzled: q^T token-major (row=t, col=c)
#define OFF_AC  32768    // u16[64][64]  XOR-swizzled: A (per-iter, wave-private rows) then C
#define OFF_ST  40960    // f32[64][4]   ||q||^2 partials per wave
#define OFF_RI  41984    // f32[64]      rinv0 per token
#define SMEM_SZ 42240

__device__ __forceinline__ u16 f2bf_rne(float f) {   // manual RNE (prep path)
  u32 u = __float_as_uint(f);
  return (u16)((u + 0x7FFFu + ((u >> 16) & 1u)) >> 16);
}
__device__ __forceinline__ u16 f2bf(float f) {       // hot path (compiler cvt)
  __hip_bfloat16 h = __float2bfloat16(f);
  return *reinterpret_cast<u16*>(&h);
}
__device__ __forceinline__ u32 pack2(float a, float b) {
  return (u32)f2bf(a) | ((u32)f2bf(b) << 16);
}

// ---- prep: Wq/Wout -> bf16; mem_norm bf16; G = mn@mn^T bf16; WM = Wout@mn^T bf16 ----
__global__ void hop_prep(const float* __restrict__ wq_f, const float* __restrict__ wo_f,
                         const float* __restrict__ memb,
                         u16* __restrict__ wq_b, u16* __restrict__ wo_b,
                         u16* __restrict__ mem_b, u16* __restrict__ G_b,
                         u16* __restrict__ WM_b) {
  int blk = blockIdx.x, tid = threadIdx.x;
  if (blk < 32) {
    int base = blk * 2048;
    #pragma unroll
    for (int i = 0; i < 8; ++i) wq_b[base + tid + 256*i] = f2bf_rne(wq_f[base + tid + 256*i]);
    return;
  }
  if (blk < 64) {
    int base = (blk - 32) * 2048;
    #pragma unroll
    for (int i = 0; i < 8; ++i) wo_b[base + tid + 256*i] = f2bf_rne(wo_f[base + tid + 256*i]);
    return;
  }
  if (blk == 64) {
    int m = tid >> 2, part = tid & 3;
    float s = 0.f;
    for (int j = 0; j < 64; ++j) { float v = memb[m*NC + part*64 + j]; s += v*v; }
    s += __shfl_xor(s, 1);
    s += __shfl_xor(s, 2);
    float inv = 1.0f / fmaxf(sqrtf(s), 1e-12f);
    for (int j = 0; j < 64; ++j) {
      int c = part*64 + j;
      mem_b[m*NC + c] = f2bf_rne(memb[m*NC + c] * inv);
    }
    return;
  }
  // blk 65: G;  blk 66..97: WM (8 o-rows each)
  __shared__ float sm[64][257];
  __shared__ float rn[64];
  for (int i = tid; i < 64*256; i += 256) { sm[i >> 8][i & 255] = memb[i]; }
  __syncthreads();
  if (tid < 64) {
    float s = 0.f;
    for (int c = 0; c < 256; ++c) { float v = sm[tid][c]; s += v*v; }
    rn[tid] = 1.0f / fmaxf(sqrtf(s), 1e-12f);
  }
  __syncthreads();
  if (blk == 65) {
    for (int i = tid; i < 4096; i += 256) {
      int m = i >> 6, mp = i & 63;
      float s = 0.f;
      for (int c = 0; c < 256; ++c) s += sm[m][c] * sm[mp][c];
      G_b[i] = f2bf_rne(s * rn[m] * rn[mp]);
    }
  } else {
    int o0 = (blk - 66) * 8;
    for (int i = tid; i < 512; i += 256) {
      int ol = i >> 6, m = i & 63;
      const float* wrow = wo_f + (size_t)(o0 + ol) * NC;
      float s = 0.f;
      for (int c = 0; c < 256; ++c) s += wrow[c] * sm[m][c];
      WM_b[(size_t)(o0 + ol) * 64 + m] = f2bf_rne(s * rn[m]);
    }
  }
}

// ---- fused main kernel: block = 64 tokens, 4 waves; iterations wave-private ----
__global__ __launch_bounds__(256, 3) void hop_main(
    const float* __restrict__ x, const float* __restrict__ bq,
    const float* __restrict__ bout, const u16* __restrict__ wq,
    const u16* __restrict__ wout, const u16* __restrict__ gmem,
    const u16* __restrict__ Gb, const u16* __restrict__ WMb,
    float* __restrict__ out) {
  __shared__ __align__(16) char smem[SMEM_SZ];
  float* StatR = (float*)(smem + OFF_ST);   // [64][4]
  float* RinvL = (float*)(smem + OFF_RI);   // [64]

  const int tid = threadIdx.x;
  const int w  = tid >> 6;
  const int l  = tid & 63;
  const int lg = l >> 4;
  const int ll = l & 15;
  const int swz = (ll & 7) << 4;            // XOR byte-swizzle keyed by row&7 (= ll&7)

  const int bimg = blockIdx.x >> 6;         // 64 blocks per image
  const int t0   = (blockIdx.x & 63) * 64;
  const float* xb = x   + (size_t)bimg * NC * NHW + t0;
  float*       ob = out + (size_t)bimg * NC * NHW + t0;

  // ================= GEMM1: q^T[o][t] = Wq[o][:]·x[:][t] + bq =================
  f32x4 acc[4][4];   // [oi][ti]: o = 64w+16oi+4lg+r, t = 16ti+ll
  #pragma unroll
  for (int oi = 0; oi < 4; ++oi)
    #pragma unroll
    for (int ti = 0; ti < 4; ++ti) acc[oi][ti] = (f32x4){0.f,0.f,0.f,0.f};
  {
    #pragma unroll
    for (int kk = 0; kk < 8; ++kk) {
      bf16x8 nf[4];                          // x columns (N-side): x[c][16ti+ll]
      #pragma unroll
      for (int ti = 0; ti < 4; ++ti) {
        const float* xc = xb + 16*ti + ll + (size_t)(32*kk + 8*lg) * NHW;
        #pragma unroll
        for (int j = 0; j < 8; ++j) nf[ti][j] = (short)f2bf(xc[(size_t)j * NHW]);
      }
      bf16x8 mf[4];                          // Wq rows (M-side)
      #pragma unroll
      for (int oi = 0; oi < 4; ++oi)
        mf[oi] = *(const bf16x8*)(wq + (size_t)(64*w + 16*oi + ll) * NC + 32*kk + 8*lg);
      #pragma unroll
      for (int oi = 0; oi < 4; ++oi)
        #pragma unroll
        for (int ti = 0; ti < 4; ++ti)
          acc[oi][ti] = __builtin_amdgcn_mfma_f32_16x16x32_bf16(mf[oi], nf[ti], acc[oi][ti], 0, 0, 0);
    }
  }
  #pragma unroll
  for (int oi = 0; oi < 4; ++oi) {
    f32x4 bv = *(const f32x4*)&bq[64*w + 16*oi + 4*lg];
    #pragma unroll
    for (int ti = 0; ti < 4; ++ti)
      #pragma unroll
      for (int r = 0; r < 4; ++r) acc[oi][ti][r] += bv[r];
  }

  // ---- ||q||^2 partials (this wave's 64 o's) -> StatR ----
  #pragma unroll
  for (int ti = 0; ti < 4; ++ti) {
    float v = 0.f;
    #pragma unroll
    for (int oi = 0; oi < 4; ++oi)
      #pragma unroll
      for (int r = 0; r < 4; ++r) { float e = acc[oi][ti][r]; v += e*e; }
    v += __shfl_xor(v, 16);
    v += __shfl_xor(v, 32);
    if (lg == 0) StatR[(16*ti + ll)*4 + w] = v;
  }

  // ---- q^T -> XZT (bf16, XOR-swizzled, row = token) ----
  #pragma unroll
  for (int oi = 0; oi < 4; ++oi)
    #pragma unroll
    for (int ti = 0; ti < 4; ++ti) {
      int row = 16*ti + ll;
      int colb = (64*w + 16*oi + 4*lg) << 1;
      uint2 v; v.x = pack2(acc[oi][ti][0], acc[oi][ti][1]);
               v.y = pack2(acc[oi][ti][2], acc[oi][ti][3]);
      *(uint2*)(smem + OFF_XZT + (row << 9) + (colb ^ swz)) = v;
    }
  __syncthreads();   // barrier #1

  // ---- rinv0 for this wave's own token (t = 16w+ll) ----
  const int t_own = 16*w + ll;
  float rinv0;
  {
    f32x4 p = *(const f32x4*)&StatR[t_own * 4];
    rinv0 = 1.0f / fmaxf(sqrtf(p[0] + p[1] + p[2] + p[3]), 1e-12f);
    if (lg == 0) RinvL[t_own] = rinv0;
  }

  // ================= P0 = rinv0 * (q @ mem^T), per-wave (16 tokens) =================
  const char* xrow = smem + OFF_XZT + (t_own << 9);
  f32x4 P[4];        // P^T[m][t]: m = 16mi+4lg+r, t = t_own
  #pragma unroll
  for (int mi = 0; mi < 4; ++mi) P[mi] = (f32x4){0.f,0.f,0.f,0.f};
  #pragma unroll
  for (int kk = 0; kk < 8; ++kk) {
    bf16x8 nf = *(const bf16x8*)(xrow + (((64*kk + 16*lg)) ^ swz));
    #pragma unroll
    for (int mi = 0; mi < 4; ++mi) {
      bf16x8 mf = *(const bf16x8*)(gmem + (size_t)(16*mi + ll) * NC + 32*kk + 8*lg);
      P[mi] = __builtin_amdgcn_mfma_f32_16x16x32_bf16(mf, nf, P[mi], 0, 0, 0);
    }
  }
  #pragma unroll
  for (int mi = 0; mi < 4; ++mi)
    #pragma unroll
    for (int r = 0; r < 4; ++r) P[mi][r] *= rinv0;

  // ---- preload G fragments (64x64, reused 3x) ----
  bf16x8 gf[4][2];
  #pragma unroll
  for (int mi = 0; mi < 4; ++mi)
    #pragma unroll
    for (int kk = 0; kk < 2; ++kk)
      gf[mi][kk] = *(const bf16x8*)(Gb + (size_t)(16*mi + ll) * 64 + 32*kk + 8*lg);

  // ================= 3 Hopfield iterations, fully wave-private =================
  char* ab_row = smem + OFF_AC + (t_own << 7);   // A/C buffer row (wave-private)
  float C[4][4];
  #pragma unroll
  for (int mi = 0; mi < 4; ++mi)
    #pragma unroll
    for (int r = 0; r < 4; ++r) C[mi][r] = 0.f;
  float n2 = 1.0f;

  #pragma unroll
  for (int k = 0; k < 3; ++k) {
    const float wk = (k == 0) ? 0.125f : (k == 1) ? 0.25f : 0.5f;
    float rinv = 1.0f / sqrtf(fmaxf(n2, 1e-24f));
    // scores + wave-local softmax over m=64 (spread across 4 lg-lanes)
    float sc[4][4];
    float mx = -1e30f;
    #pragma unroll
    for (int mi = 0; mi < 4; ++mi)
      #pragma unroll
      for (int r = 0; r < 4; ++r) { sc[mi][r] = P[mi][r] * rinv; mx = fmaxf(mx, sc[mi][r]); }
    mx = fmaxf(mx, __shfl_xor(mx, 16));
    mx = fmaxf(mx, __shfl_xor(mx, 32));
    float A[4][4];
    float S = 0.f;
    #pragma unroll
    for (int mi = 0; mi < 4; ++mi)
      #pragma unroll
      for (int r = 0; r < 4; ++r) { float e = __expf(sc[mi][r] - mx); A[mi][r] = e; S += e; }
    S += __shfl_xor(S, 16);
    S += __shfl_xor(S, 32);
    float sinv = 1.0f / S;
    float dPA = 0.f;
    #pragma unroll
    for (int mi = 0; mi < 4; ++mi)
      #pragma unroll
      for (int r = 0; r < 4; ++r) {
        A[mi][r] *= sinv;
        dPA += A[mi][r] * P[mi][r];
        C[mi][r] += wk * A[mi][r];
      }
    dPA += __shfl_xor(dPA, 16);
    dPA += __shfl_xor(dPA, 32);
    // A -> LDS bf16 (wave-private, in-order DS pipe)
    #pragma unroll
    for (int mi = 0; mi < 4; ++mi) {
      uint2 v; v.x = pack2(A[mi][0], A[mi][1]); v.y = pack2(A[mi][2], A[mi][3]);
      *(uint2*)(ab_row + (((32*mi + 8*lg)) ^ swz)) = v;
    }
    // V = A @ G via MFMA
    f32x4 V[4];
    #pragma unroll
    for (int mi = 0; mi < 4; ++mi) V[mi] = (f32x4){0.f,0.f,0.f,0.f};
    #pragma unroll
    for (int kk = 0; kk < 2; ++kk) {
      bf16x8 nf = *(const bf16x8*)(ab_row + (((64*kk + 16*lg)) ^ swz));
      #pragma unroll
      for (int mi = 0; mi < 4; ++mi)
        V[mi] = __builtin_amdgcn_mfma_f32_16x16x32_bf16(gf[mi][kk], nf, V[mi], 0, 0, 0);
    }
    float dVA = 0.f;
    #pragma unroll
    for (int mi = 0; mi < 4; ++mi)
      #pragma unroll
      for (int r = 0; r < 4; ++r) {
        dVA += A[mi][r] * V[mi][r];
        P[mi][r] = 0.5f * (P[mi][r] + V[mi][r]);
      }
    dVA += __shfl_xor(dVA, 16);
    dVA += __shfl_xor(dVA, 32);
    n2 = 0.25f * n2 + 0.5f * dPA + 0.25f * dVA;
  }

  // ---- C -> LDS bf16 (same buffer; A reads are done) ----
  #pragma unroll
  for (int mi = 0; mi < 4; ++mi) {
    uint2 v; v.x = pack2(C[mi][0], C[mi][1]); v.y = pack2(C[mi][2], C[mi][3]);
    *(uint2*)(ab_row + (((32*mi + 8*lg)) ^ swz)) = v;
  }
  __syncthreads();   // barrier #2

  // ================= out = 0.125*rinv0*(Wout q) + WM*C + bout + x =================
  #pragma unroll
  for (int oi = 0; oi < 4; ++oi)
    #pragma unroll
    for (int ti = 0; ti < 4; ++ti) acc[oi][ti] = (f32x4){0.f,0.f,0.f,0.f};
  // Wout @ q (from XZT)
  #pragma unroll
  for (int kk = 0; kk < 8; ++kk) {
    bf16x8 nf[4];
    #pragma unroll
    for (int ti = 0; ti < 4; ++ti)
      nf[ti] = *(const bf16x8*)(smem + OFF_XZT + ((16*ti + ll) << 9) + (((64*kk + 16*lg)) ^ swz));
    bf16x8 mf[4];
    #pragma unroll
    for (int oi = 0; oi < 4; ++oi)
      mf[oi] = *(const bf16x8*)(wout + (size_t)(64*w + 16*oi + ll) * NC + 32*kk + 8*lg);
    #pragma unroll
    for (int oi = 0; oi < 4; ++oi)
      #pragma unroll
      for (int ti = 0; ti < 4; ++ti)
        acc[oi][ti] = __builtin_amdgcn_mfma_f32_16x16x32_bf16(mf[oi], nf[ti], acc[oi][ti], 0, 0, 0);
  }
  // scale by 0.125*rinv0[t]
  #pragma unroll
  for (int ti = 0; ti < 4; ++ti) {
    float rv = 0.125f * RinvL[16*ti + ll];
    #pragma unroll
    for (int oi = 0; oi < 4; ++oi)
      #pragma unroll
      for (int r = 0; r < 4; ++r) acc[oi][ti][r] *= rv;
  }
  // += WM @ C (from AC buffer)
  #pragma unroll
  for (int kk = 0; kk < 2; ++kk) {
    bf16x8 nf[4];
    #pragma unroll
    for (int ti = 0; ti < 4; ++ti)
      nf[ti] = *(const bf16x8*)(smem + OFF_AC + ((16*ti + ll) << 7) + (((64*kk + 16*lg)) ^ swz));
    bf16x8 mf[4];
    #pragma unroll
    for (int oi = 0; oi < 4; ++oi)
      mf[oi] = *(const bf16x8*)(WMb + (size_t)(64*w + 16*oi + ll) * 64 + 32*kk + 8*lg);
    #pragma unroll
    for (int oi = 0; oi < 4; ++oi)
      #pragma unroll
      for (int ti = 0; ti < 4; ++ti)
        acc[oi][ti] = __builtin_amdgcn_mfma_f32_16x16x32_bf16(mf[oi], nf[ti], acc[oi][ti], 0, 0, 0);
  }
  // + bout, + residual, store
  #pragma unroll
  for (int oi = 0; oi < 4; ++oi) {
    f32x4 bv = *(const f32x4*)&bout[64*w + 16*oi + 4*lg];
    #pragma unroll
    for (int r = 0; r < 4; ++r) {
      const size_t o = (size_t)(64*w + 16*oi + 4*lg + r) * NHW;
      #pragma unroll
      for (int ti = 0; ti < 4; ++ti) {
        size_t idx = o + 16*ti + ll;
        ob[idx] = acc[oi][ti][r] + bv[r] + xb[idx];
      }
    }
  }
}

extern "C" void kernel_launch(void* const* d_in, const int* in_sizes, int n_in,
                              void* d_out, int out_size, void* d_ws, size_t ws_size,
                              hipStream_t stream) {
  const float* x    = (const float*)d_in[0];
  const float* memb = (const float*)d_in[1];
  const float* Wq   = (const float*)d_in[2];
  const float* bq   = (const float*)d_in[3];
  const float* Wout = (const float*)d_in[4];
  const float* bout = (const float*)d_in[5];
  float* out = (float*)d_out;

  u16* wq_b   = (u16*)d_ws;                 // 65536
  u16* wout_b = wq_b + 65536;               // 65536
  u16* mem_b  = wq_b + 131072;              // 16384
  u16* G_b    = wq_b + 147456;              // 4096
  u16* WM_b   = wq_b + 151552;              // 16384

  hop_prep<<<98, 256, 0, stream>>>(Wq, Wout, memb, wq_b, wout_b, mem_b, G_b, WM_b);
  hop_main<<<1024, 256, 0, stream>>>(x, bq, bout, wq_b, wout_b, mem_b, G_b, WM_b, out);
}